// Round 1
// 304.838 us; speedup vs baseline: 1.0330x; 1.0330x over previous
//
#include <hip/hip_runtime.h>
#include <hip/hip_bf16.h>

// ---------------------------------------------------------------------------
// MoE dense all-expert forward, MI355X / gfx950.  B=16384, D=H=O=256, E=32.
// Round 5: occupancy + pipeline rebuild.
//  k0: cvt_w : W1,W2 f32 -> bf16, per-(expert, wave-slot[16], kb) 2 KB chunks.
//  k1: moe   : 256 blocks x 1024 thr (16 waves -> 4 waves/SIMD).
//      - crews of 8 waves: crew0 = GEMM1(e), crew1 = GEMM2(e-1); each wave
//        owns a 32-col slot (slots 0-7 = W1 rows, 8-15 = W2 rows).
//      - h_s double-buffered -> ONE barrier per expert phase (33 total);
//        crew0 epilogue overlaps crew1 MFMA tail.
//      - weight stream register-prefetched TWO kb-chunks ahead (buf[2][2]),
//        flowing across expert boundaries and barriers.
//      - s_setprio(1) around MFMA clusters (role-diverse waves per SIMD).
// ---------------------------------------------------------------------------

typedef __attribute__((ext_vector_type(8))) short bf16x8;   // 8 bf16 = 4 VGPRs
typedef __attribute__((ext_vector_type(4))) float f32x4;

__device__ __forceinline__ unsigned short f2bf(float f) {
    unsigned u = __builtin_bit_cast(unsigned, f);
    u += 0x7FFFu + ((u >> 16) & 1u);        // round-to-nearest-even
    return (unsigned short)(u >> 16);
}
__device__ __forceinline__ unsigned pack_bf16x2(float a, float b) {
    return (unsigned)f2bf(a) | ((unsigned)f2bf(b) << 16);
}

// 16B-chunk XOR swizzle for [64 rows][256 elem] bf16 tiles (index in ushorts)
#define LX(r, ch) (((r) << 8) + ((((ch) ^ ((r) & 7))) << 3))

// ------------------- W f32 -> bf16 convert + tile reorder ------------------
// Chunk c = (e*16 + slot)*8 + kb (slot 0-7 -> W1 rows slot*32.., 8-15 -> W2
// rows (slot-8)*32..). Chunk = 1024 bf16 = 2 KB, element order (t, lane, j):
// row = slot32 + t*16 + (lane&15), k = kb*32 + (lane>>4)*8 + j  — exactly the
// mfma_16x16x32 A-frag order (two 16-row sub-frags per slot).
__global__ __launch_bounds__(256) void cvt_w(const float* __restrict__ W1,
                                             const float* __restrict__ W2,
                                             unsigned short* __restrict__ Wr) {
    int T = blockIdx.x * 256 + threadIdx.x;          // 524288 threads
    int lane = T & 63, t = (T >> 6) & 1, kb = (T >> 7) & 7;
    int s = (T >> 10) & 15, e = T >> 14;
    int l15 = lane & 15, quad = lane >> 4;
    int row = (s & 7) * 32 + t * 16 + l15;
    const float* src = ((s < 8) ? W1 : W2) +
                       ((long)e * 256 + row) * 256 + kb * 32 + quad * 8;
    float4 v0 = ((const float4*)src)[0], v1 = ((const float4*)src)[1];
    uint4 o;
    o.x = pack_bf16x2(v0.x, v0.y); o.y = pack_bf16x2(v0.z, v0.w);
    o.z = pack_bf16x2(v1.x, v1.y); o.w = pack_bf16x2(v1.z, v1.w);
    ((uint4*)Wr)[T] = o;     // uint4 index == T by construction
}

// ------------------------------ fused MoE ----------------------------------
__global__ __launch_bounds__(1024, 4) void moe_kernel(
    const float* __restrict__ x,
    const unsigned short* __restrict__ Wr,
    const float* __restrict__ bias1,
    const float* __restrict__ b2,
    const float* __restrict__ Wg,
    const float* __restrict__ bg,
    float* __restrict__ out)
{
    __shared__ __align__(16) unsigned short x_s[64 * 256];      // 32 KB
    __shared__ __align__(16) unsigned short h_s[2][64 * 256];   // 64 KB dbuf
    __shared__ float gws[64 * 33];                              // gate weights

    const int tid  = threadIdx.x;
    const int wv   = tid >> 6, lane = tid & 63;
    const int quad = lane >> 4, l15 = lane & 15;
    const int crew = wv >> 3, g = wv & 7;      // crew0 = GEMM1, crew1 = GEMM2
    const int row0 = blockIdx.x * 64;

    // ---- stage x tile: f32 global -> bf16 LDS (swizzled) ----
#pragma unroll
    for (int c = 0; c < 2; ++c) {
        int chunk = tid + c * 1024;             // 2048 chunks of 8 elems
        int r = chunk >> 5, ch = chunk & 31;
        const float4* s = (const float4*)(x + (long)(row0 + r) * 256 + ch * 8);
        float4 v0 = s[0], v1 = s[1];
        uint4 o;
        o.x = pack_bf16x2(v0.x, v0.y); o.y = pack_bf16x2(v0.z, v0.w);
        o.z = pack_bf16x2(v1.x, v1.y); o.w = pack_bf16x2(v1.z, v1.w);
        *(uint4*)(&x_s[LX(r, ch)]) = o;
    }

    // ---- inline gating: 4 rows per wave, all f32 (matches reference) ----
    {
        const int e32 = lane & 31, half = lane >> 5;
        const float4* wg4 = (const float4*)(Wg + e32 * 256 + half * 128);
        float bgv = bg[e32];
        for (int i = 0; i < 4; ++i) {
            int lr = wv * 4 + i;
            const float4* xr4 = (const float4*)(x + (long)(row0 + lr) * 256 + half * 128);
            float acc = 0.f;
#pragma unroll
            for (int tt = 0; tt < 32; ++tt) {
                float4 w = wg4[tt], xv = xr4[tt];
                acc = fmaf(w.x, xv.x, acc); acc = fmaf(w.y, xv.y, acc);
                acc = fmaf(w.z, xv.z, acc); acc = fmaf(w.w, xv.w, acc);
            }
            acc += __shfl_xor(acc, 32);
            float score = (acc + bgv) / 2.71828182845904523f;   // TEMP = e

            float m = score;
#pragma unroll
            for (int d = 16; d >= 1; d >>= 1) m = fmaxf(m, __shfl_xor(m, d));
            float p = expf(score - m);
            float ps = p;
#pragma unroll
            for (int d = 16; d >= 1; d >>= 1) ps += __shfl_xor(ps, d);
            float prob = p / ps;

            int rank = 0;
#pragma unroll
            for (int j = 0; j < 32; ++j) {
                float pj = __shfl(prob, j);
                rank += (pj > prob || (pj == prob && j < e32)) ? 1 : 0;
            }
            float kept = (rank < 22) ? prob : 0.f;
            float wsum = kept;
#pragma unroll
            for (int d = 16; d >= 1; d >>= 1) wsum += __shfl_xor(wsum, d);
            float weight = kept / (wsum + 1e-8f);

            if (half == 0) gws[lr * 33 + e32] = weight;
        }
    }

    __syncthreads();   // x_s + gws ready

    // ---- crew1: out^T accumulators, init = sum_e gw*b2 (in-block bias2) ----
    f32x4 oacc[2][4];                           // [ot][rt]
#pragma unroll
    for (int ot = 0; ot < 2; ++ot)
#pragma unroll
        for (int rt = 0; rt < 4; ++rt) {
            f32x4 z = {0.f, 0.f, 0.f, 0.f};
            oacc[ot][rt] = z;
        }
    if (crew == 1) {
        for (int ee = 0; ee < 32; ++ee) {
            float gv[4];
#pragma unroll
            for (int rt = 0; rt < 4; ++rt) gv[rt] = gws[(rt * 16 + l15) * 33 + ee];
#pragma unroll
            for (int ot = 0; ot < 2; ++ot) {
                float4 bb = *(const float4*)(b2 + ee * 256 + g * 32 + ot * 16 + quad * 4);
#pragma unroll
                for (int rt = 0; rt < 4; ++rt) {
                    oacc[ot][rt][0] = fmaf(gv[rt], bb.x, oacc[ot][rt][0]);
                    oacc[ot][rt][1] = fmaf(gv[rt], bb.y, oacc[ot][rt][1]);
                    oacc[ot][rt][2] = fmaf(gv[rt], bb.z, oacc[ot][rt][2]);
                    oacc[ot][rt][3] = fmaf(gv[rt], bb.w, oacc[ot][rt][3]);
                }
            }
        }
    }

    // ---- preload weight chunks kb=0,1 (expert 0, slot wv) -> depth-2 ring --
    bf16x8 buf[2][2];                           // [ring][t]
    {
        const unsigned short* p0 = Wr + (long)wv * 8192;   // chunk wv*8
        buf[0][0] = *(const bf16x8*)(p0 + lane * 8);
        buf[0][1] = *(const bf16x8*)(p0 + 512 + lane * 8);
        buf[1][0] = *(const bf16x8*)(p0 + 1024 + lane * 8);
        buf[1][1] = *(const bf16x8*)(p0 + 1536 + lane * 8);
    }

    // ---- expert pipeline: crew0 computes e, crew1 computes e-1 ----
    // one barrier per phase: crew0 writes h_s[e&1], crew1 reads h_s[(e-1)&1]
    for (int e = 0; e <= 32; ++e) {
        if (crew == 0) {
            if (e < 32) {
                f32x4 hacc[2][4];               // [ht][rt]
#pragma unroll
                for (int ht = 0; ht < 2; ++ht)
#pragma unroll
                    for (int rt = 0; rt < 4; ++rt) {
                        f32x4 z = {0.f, 0.f, 0.f, 0.f};
                        hacc[ht][rt] = z;
                    }
                const unsigned short* w_e = Wr + ((long)(e * 16 + wv) * 8) * 1024;
#pragma unroll
                for (int kb = 0; kb < 8; ++kb) {
                    bf16x8 a0 = buf[kb & 1][0], a1 = buf[kb & 1][1];
                    // prefetch kb+2 (crosses into expert e+1 at kb>=6)
                    const unsigned short* np =
                        w_e + ((kb < 6) ? (kb + 2) : (128 + kb - 6)) * 1024;
                    buf[kb & 1][0] = *(const bf16x8*)(np + lane * 8);
                    buf[kb & 1][1] = *(const bf16x8*)(np + 512 + lane * 8);
                    bf16x8 bbv[4];
#pragma unroll
                    for (int rt = 0; rt < 4; ++rt)
                        bbv[rt] = *(const bf16x8*)(&x_s[LX(rt * 16 + l15, kb * 4 + quad)]);
                    __builtin_amdgcn_s_setprio(1);
#pragma unroll
                    for (int rt = 0; rt < 4; ++rt) {
                        hacc[0][rt] = __builtin_amdgcn_mfma_f32_16x16x32_bf16(
                            a0, bbv[rt], hacc[0][rt], 0, 0, 0);
                        hacc[1][rt] = __builtin_amdgcn_mfma_f32_16x16x32_bf16(
                            a1, bbv[rt], hacc[1][rt], 0, 0, 0);
                    }
                    __builtin_amdgcn_s_setprio(0);
                }
                // epilogue: +b1, relu, * gate weight, packed b64 -> h_s[e&1]
                unsigned short* hb = h_s[e & 1];
                float4 bv[2]; float gw[4];
#pragma unroll
                for (int ht = 0; ht < 2; ++ht)
                    bv[ht] = *(const float4*)(bias1 + e * 256 + g * 32 + ht * 16 + quad * 4);
#pragma unroll
                for (int rt = 0; rt < 4; ++rt)
                    gw[rt] = gws[(rt * 16 + l15) * 33 + e];
#pragma unroll
                for (int ht = 0; ht < 2; ++ht) {
                    int hcol = g * 32 + ht * 16 + quad * 4;  // 4 consecutive h-cols
                    int ch = hcol >> 3, off = hcol & 7;
#pragma unroll
                    for (int rt = 0; rt < 4; ++rt) {
                        int r = rt * 16 + l15;
                        float v0 = fmaxf(hacc[ht][rt][0] + bv[ht].x, 0.f) * gw[rt];
                        float v1 = fmaxf(hacc[ht][rt][1] + bv[ht].y, 0.f) * gw[rt];
                        float v2 = fmaxf(hacc[ht][rt][2] + bv[ht].z, 0.f) * gw[rt];
                        float v3 = fmaxf(hacc[ht][rt][3] + bv[ht].w, 0.f) * gw[rt];
                        uint2 pk;
                        pk.x = pack_bf16x2(v0, v1);
                        pk.y = pack_bf16x2(v2, v3);
                        *(uint2*)(&hb[(r << 8) + ((ch ^ (r & 7)) << 3) + off]) = pk;
                    }
                }
            }
        } else {
            if (e >= 1) {
                const int me = e - 1;
                const unsigned short* w_e = Wr + ((long)(me * 16 + wv) * 8) * 1024;
                const unsigned short* hbuf = h_s[me & 1];
#pragma unroll
                for (int kb = 0; kb < 8; ++kb) {
                    bf16x8 a0 = buf[kb & 1][0], a1 = buf[kb & 1][1];
                    const unsigned short* np =
                        w_e + ((kb < 6) ? (kb + 2) : (128 + kb - 6)) * 1024;
                    buf[kb & 1][0] = *(const bf16x8*)(np + lane * 8);
                    buf[kb & 1][1] = *(const bf16x8*)(np + 512 + lane * 8);
                    bf16x8 bbv[4];
#pragma unroll
                    for (int rt = 0; rt < 4; ++rt)
                        bbv[rt] = *(const bf16x8*)(&hbuf[LX(rt * 16 + l15, kb * 4 + quad)]);
                    __builtin_amdgcn_s_setprio(1);
#pragma unroll
                    for (int rt = 0; rt < 4; ++rt) {
                        oacc[0][rt] = __builtin_amdgcn_mfma_f32_16x16x32_bf16(
                            a0, bbv[rt], oacc[0][rt], 0, 0, 0);
                        oacc[1][rt] = __builtin_amdgcn_mfma_f32_16x16x32_bf16(
                            a1, bbv[rt], oacc[1][rt], 0, 0, 0);
                    }
                    __builtin_amdgcn_s_setprio(0);
                }
            }
        }

        __syncthreads();   // h_s[e&1] final; crew1 done with h_s[(e-1)&1]
    }

    // ---- final store: out^T frags -> out ----
    if (crew == 1) {
#pragma unroll
        for (int ot = 0; ot < 2; ++ot)
#pragma unroll
            for (int rt = 0; rt < 4; ++rt)
                *(f32x4*)(out + (long)(row0 + rt * 16 + l15) * 256 +
                          g * 32 + ot * 16 + quad * 4) = oacc[ot][rt];
    }
}

// ------------------------------- launch ------------------------------------
extern "C" void kernel_launch(void* const* d_in, const int* in_sizes, int n_in,
                              void* d_out, int out_size, void* d_ws, size_t ws_size,
                              hipStream_t stream) {
    (void)in_sizes; (void)n_in; (void)out_size; (void)ws_size;
    const float* x  = (const float*)d_in[0];   // [16384,256]
    const float* W1 = (const float*)d_in[1];   // [32,256,256]
    const float* b1 = (const float*)d_in[2];   // [32,256]
    const float* W2 = (const float*)d_in[3];   // [32,256,256]
    const float* b2 = (const float*)d_in[4];   // [32,256]
    const float* Wg = (const float*)d_in[5];   // [32,256]
    const float* bg = (const float*)d_in[6];   // [32]
    float* out = (float*)d_out;                // [16384,256]

    // ws: Wr = 33 experts (32 real + 1 prefetch-overrun pad) x 256 KB
    unsigned short* Wr = (unsigned short*)d_ws;

    cvt_w<<<2048, 256, 0, stream>>>(W1, W2, Wr);
    moe_kernel<<<256, 1024, 0, stream>>>(x, Wr, b1, b2, Wg, bg, out);
}